// Round 4
// baseline (123.324 us; speedup 1.0000x reference)
//
#include <hip/hip_runtime.h>
#include <hip/hip_bf16.h>

#define N_TOT 4096
#define D     512
#define BHALF 2048

// exp(2s) = 2^(s * 2*log2(e))
#define EXP2_SCALE 2.8853900817779268f
// exp(2*S_ii) for a normalized row (S_ii = 1 +- ~1e-4 in bf16; error in the
// final log is ~4e-7 -- negligible vs the 0.166 threshold)
#define E2 7.3890560989306495f

typedef __attribute__((ext_vector_type(8))) short short8;
typedef __attribute__((ext_vector_type(4))) float floatx4;

#define AS_GLOBAL(p) ((const __attribute__((address_space(1))) void*)(p))
#define AS_LDS(p)    ((__attribute__((address_space(3))) void*)(p))

// ---------------- kernel 1: normalize rows, cast to bf16 ------------------
// 1024 blocks x 256 threads; one 64-lane wave per row, no LDS, no barrier.
// Also zeroes rowsum[] and the grid-completion counter (ws is re-poisoned
// to 0xAA before every timed call, so this must happen every call).
__global__ void normalize_kernel(const float* __restrict__ z_i,
                                 const float* __restrict__ z_j,
                                 short* __restrict__ zn,
                                 float* __restrict__ rowsum,
                                 unsigned int* __restrict__ done) {
    const int wave = threadIdx.x >> 6, lane = threadIdx.x & 63;
    const int row = blockIdx.x * 4 + wave;
    const float* src = (row < BHALF) ? (z_i + (size_t)row * D)
                                     : (z_j + (size_t)(row - BHALF) * D);
    if (lane == 0) rowsum[row] = 0.0f;
    if (blockIdx.x == 0 && threadIdx.x == 0) *done = 0u;
    float4 v0 = ((const float4*)src)[lane];
    float4 v1 = ((const float4*)src)[lane + 64];
    float ss = v0.x*v0.x + v0.y*v0.y + v0.z*v0.z + v0.w*v0.w
             + v1.x*v1.x + v1.y*v1.y + v1.z*v1.z + v1.w*v1.w;
    #pragma unroll
    for (int off = 32; off > 0; off >>= 1) ss += __shfl_xor(ss, off);
    float inv = 1.0f / fmaxf(sqrtf(ss), 1e-8f);
    short4 o0, o1;
    o0.x = (short)__bfloat16_as_ushort(__float2bfloat16(v0.x * inv));
    o0.y = (short)__bfloat16_as_ushort(__float2bfloat16(v0.y * inv));
    o0.z = (short)__bfloat16_as_ushort(__float2bfloat16(v0.z * inv));
    o0.w = (short)__bfloat16_as_ushort(__float2bfloat16(v0.w * inv));
    o1.x = (short)__bfloat16_as_ushort(__float2bfloat16(v1.x * inv));
    o1.y = (short)__bfloat16_as_ushort(__float2bfloat16(v1.y * inv));
    o1.z = (short)__bfloat16_as_ushort(__float2bfloat16(v1.z * inv));
    o1.w = (short)__bfloat16_as_ushort(__float2bfloat16(v1.w * inv));
    ((short4*)(zn + (size_t)row * D))[lane]      = o0;
    ((short4*)(zn + (size_t)row * D))[lane + 64] = o1;
}

// ------- kernel 2: fused symmetric GEMM + exp + row-sum + finalize --------
// Triangular grid: 528 blocks of 256 threads; block -> (bi, bj), bj>=bi.
// Double-buffered LDS, global_load_lds prefetch, one barrier per k-iter.
// The last block to finish the epilogue computes the final loss (avoids a
// third dispatch).
__launch_bounds__(256)
__global__ void gemm_fused(const short* __restrict__ zn,
                           float* __restrict__ rowsum,
                           float* __restrict__ spos,
                           unsigned int* __restrict__ done,
                           float* __restrict__ out) {
    __shared__ short At[2][128 * 32];
    __shared__ short Bt[2][128 * 32];

    // triangular decode (scalar, <=32 iters)
    int b = blockIdx.x, bi = 0, rowlen = 32;
    while (b >= rowlen) { b -= rowlen; rowlen--; bi++; }
    const int bj = bi + b;
    const int i0 = bi * 128;
    const int j0 = bj * 128;

    const int t = threadIdx.x;
    const int lane = t & 63, wave = t >> 6;
    const int wm = wave & 1, wn = wave >> 1;     // 2x2 waves -> 64x64 each
    const int quad = lane >> 4, l16 = lane & 15;

    // staging: lane L covers row L>>2, 16B chunk L&3 ->
    // LDS offset = wave base + lane*16 (contiguous; global_load_lds rule)
    const int sr = lane >> 2;
    const int sc = (lane & 3) * 8;
    const short* gA0 = zn + (size_t)(i0 + wave * 32 + sr)      * D + sc;
    const short* gA1 = zn + (size_t)(i0 + wave * 32 + 16 + sr) * D + sc;
    const short* gB0 = zn + (size_t)(j0 + wave * 32 + sr)      * D + sc;
    const short* gB1 = zn + (size_t)(j0 + wave * 32 + 16 + sr) * D + sc;
    const int lo0 = (wave * 32)      * 32;
    const int lo1 = (wave * 32 + 16) * 32;

    floatx4 acc[4][4] = {};

    __builtin_amdgcn_global_load_lds(AS_GLOBAL(gA0), AS_LDS(&At[0][lo0]), 16, 0, 0);
    __builtin_amdgcn_global_load_lds(AS_GLOBAL(gA1), AS_LDS(&At[0][lo1]), 16, 0, 0);
    __builtin_amdgcn_global_load_lds(AS_GLOBAL(gB0), AS_LDS(&Bt[0][lo0]), 16, 0, 0);
    __builtin_amdgcn_global_load_lds(AS_GLOBAL(gB1), AS_LDS(&Bt[0][lo1]), 16, 0, 0);

    for (int kt = 0; kt < 16; ++kt) {
        const int cur = kt & 1;
        __syncthreads();                 // drains vmcnt -> buf[cur] ready
        if (kt < 15) {
            const int nxt = 1 - cur;
            const int ko = (kt + 1) * 32;
            __builtin_amdgcn_global_load_lds(AS_GLOBAL(gA0 + ko), AS_LDS(&At[nxt][lo0]), 16, 0, 0);
            __builtin_amdgcn_global_load_lds(AS_GLOBAL(gA1 + ko), AS_LDS(&At[nxt][lo1]), 16, 0, 0);
            __builtin_amdgcn_global_load_lds(AS_GLOBAL(gB0 + ko), AS_LDS(&Bt[nxt][lo0]), 16, 0, 0);
            __builtin_amdgcn_global_load_lds(AS_GLOBAL(gB1 + ko), AS_LDS(&Bt[nxt][lo1]), 16, 0, 0);
        }
        short8 af[4], bf[4];
        #pragma unroll
        for (int tm = 0; tm < 4; ++tm)
            af[tm] = *(const short8*)(&At[cur][(wm*64 + tm*16 + l16) * 32 + quad*8]);
        #pragma unroll
        for (int tn = 0; tn < 4; ++tn)
            bf[tn] = *(const short8*)(&Bt[cur][(wn*64 + tn*16 + l16) * 32 + quad*8]);
        #pragma unroll
        for (int tm = 0; tm < 4; ++tm)
            #pragma unroll
            for (int tn = 0; tn < 4; ++tn)
                acc[tm][tn] = __builtin_amdgcn_mfma_f32_16x16x32_bf16(
                    af[tm], bf[tn], acc[tm][tn], 0, 0, 0);
    }

    // epilogue: e = exp(2s). Row sums -> rows I; column sums -> rows J
    // (off-diagonal tiles; S symmetric).
    float cs[4] = {0.f, 0.f, 0.f, 0.f};
    #pragma unroll
    for (int tm = 0; tm < 4; ++tm) {
        float rs[4] = {0.f, 0.f, 0.f, 0.f};
        #pragma unroll
        for (int tn = 0; tn < 4; ++tn)
            #pragma unroll
            for (int r = 0; r < 4; ++r) {
                float e = exp2f(acc[tm][tn][r] * EXP2_SCALE);
                rs[r] += e;
                cs[tn] += e;
            }
        #pragma unroll
        for (int r = 0; r < 4; ++r) {
            float v = rs[r];
            v += __shfl_xor(v, 1);
            v += __shfl_xor(v, 2);
            v += __shfl_xor(v, 4);
            v += __shfl_xor(v, 8);
            if (l16 == 0) {
                int gi = i0 + wm*64 + tm*16 + quad*4 + r;
                atomicAdd(&rowsum[gi], v);
            }
        }
    }
    if (bi != bj) {
        #pragma unroll
        for (int tn = 0; tn < 4; ++tn) {
            float v = cs[tn];
            v += __shfl_xor(v, 16);
            v += __shfl_xor(v, 32);
            if (quad == 0) {
                int gj = j0 + wn*64 + tn*16 + l16;
                atomicAdd(&rowsum[gj], v);
            }
        }
    }
    // positive pairs (j = i + 2048) live exactly in blocks bj == bi+16
    if (bj == bi + 16) {
        #pragma unroll
        for (int tm = 0; tm < 4; ++tm)
            #pragma unroll
            for (int tn = 0; tn < 4; ++tn)
                #pragma unroll
                for (int r = 0; r < 4; ++r) {
                    int li = wm*64 + tm*16 + quad*4 + r;   // local row
                    int lj = wn*64 + tn*16 + l16;          // local col
                    if (li == lj) {
                        float s = acc[tm][tn][r];
                        spos[i0 + li]         = s;
                        spos[i0 + li + BHALF] = s;
                    }
                }
    }

    // ---- last-block finalize: the 528th block to arrive computes the loss
    __syncthreads();
    __threadfence();                               // release our stores/atomics
    __shared__ int is_last;
    if (t == 0) is_last = (atomicAdd(done, 1u) == 527u) ? 1 : 0;
    __syncthreads();
    if (is_last) {
        __threadfence();                           // acquire side
        float acc2 = 0.f;
        for (int i = t; i < N_TOT; i += 256) {
            float sp = __hip_atomic_load(&spos[i],   __ATOMIC_RELAXED,
                                         __HIP_MEMORY_SCOPE_AGENT);
            float rs = __hip_atomic_load(&rowsum[i], __ATOMIC_RELAXED,
                                         __HIP_MEMORY_SCOPE_AGENT);
            float denom = rs - E2 + exp2f(sp * EXP2_SCALE);
            acc2 += __logf(denom) - 2.0f * sp;
        }
        #pragma unroll
        for (int off = 32; off > 0; off >>= 1) acc2 += __shfl_down(acc2, off);
        __shared__ float red[4];
        if ((t & 63) == 0) red[t >> 6] = acc2;
        __syncthreads();
        if (t == 0)
            out[0] = (red[0] + red[1] + red[2] + red[3]) / (float)N_TOT;
    }
}

extern "C" void kernel_launch(void* const* d_in, const int* in_sizes, int n_in,
                              void* d_out, int out_size, void* d_ws, size_t ws_size,
                              hipStream_t stream) {
    const float* z_i = (const float*)d_in[0];
    const float* z_j = (const float*)d_in[1];
    float* out = (float*)d_out;

    char* ws = (char*)d_ws;
    short* zn           = (short*)ws;                              // 4 MB
    float* rowsum       = (float*)(ws + (size_t)N_TOT * D * 2);    // 16 KB
    float* spos         = rowsum + N_TOT;                          // 16 KB
    unsigned int* done  = (unsigned int*)(spos + N_TOT);           // 4 B

    normalize_kernel<<<N_TOT / 4, 256, 0, stream>>>(z_i, z_j, zn, rowsum, done);
    gemm_fused<<<(32 * 33) / 2, 256, 0, stream>>>(zn, rowsum, spos, done, out);
}

// Round 5
// 89.941 us; speedup vs baseline: 1.3712x; 1.3712x over previous
//
#include <hip/hip_runtime.h>
#include <hip/hip_bf16.h>

#define N_TOT 4096
#define D     512
#define BHALF 2048

// exp(2s) = 2^(s * 2*log2(e))
#define EXP2_SCALE 2.8853900817779268f
// exp(2*S_ii) for a normalized row (S_ii = 1 +- ~1e-4 in bf16; error in the
// final log is ~4e-7 -- negligible vs the 0.166 threshold)
#define E2 7.3890560989306495f

typedef __attribute__((ext_vector_type(8))) short short8;
typedef __attribute__((ext_vector_type(4))) float floatx4;

#define AS_GLOBAL(p) ((const __attribute__((address_space(1))) void*)(p))
#define AS_LDS(p)    ((__attribute__((address_space(3))) void*)(p))

// ---------------- kernel 1: normalize rows, cast to bf16 (+ zero rowsum) ----
// 1024 blocks x 256 threads; one 64-lane wave per row, no LDS, no barrier.
__global__ void normalize_kernel(const float* __restrict__ z_i,
                                 const float* __restrict__ z_j,
                                 short* __restrict__ zn,
                                 float* __restrict__ rowsum) {
    const int wave = threadIdx.x >> 6, lane = threadIdx.x & 63;
    const int row = blockIdx.x * 4 + wave;
    const float* src = (row < BHALF) ? (z_i + (size_t)row * D)
                                     : (z_j + (size_t)(row - BHALF) * D);
    if (lane == 0) rowsum[row] = 0.0f;         // replaces hipMemsetAsync
    float4 v0 = ((const float4*)src)[lane];
    float4 v1 = ((const float4*)src)[lane + 64];
    float ss = v0.x*v0.x + v0.y*v0.y + v0.z*v0.z + v0.w*v0.w
             + v1.x*v1.x + v1.y*v1.y + v1.z*v1.z + v1.w*v1.w;
    #pragma unroll
    for (int off = 32; off > 0; off >>= 1) ss += __shfl_xor(ss, off);
    float inv = 1.0f / fmaxf(sqrtf(ss), 1e-8f);
    short4 o0, o1;
    o0.x = (short)__bfloat16_as_ushort(__float2bfloat16(v0.x * inv));
    o0.y = (short)__bfloat16_as_ushort(__float2bfloat16(v0.y * inv));
    o0.z = (short)__bfloat16_as_ushort(__float2bfloat16(v0.z * inv));
    o0.w = (short)__bfloat16_as_ushort(__float2bfloat16(v0.w * inv));
    o1.x = (short)__bfloat16_as_ushort(__float2bfloat16(v1.x * inv));
    o1.y = (short)__bfloat16_as_ushort(__float2bfloat16(v1.y * inv));
    o1.z = (short)__bfloat16_as_ushort(__float2bfloat16(v1.z * inv));
    o1.w = (short)__bfloat16_as_ushort(__float2bfloat16(v1.w * inv));
    ((short4*)(zn + (size_t)row * D))[lane]      = o0;
    ((short4*)(zn + (size_t)row * D))[lane + 64] = o1;
}

// ---------------- kernel 2: fused symmetric GEMM + exp + row-sum ----------
// Triangular grid: 528 blocks of 256 threads; block -> (bi, bj), bj>=bi.
// Double-buffered LDS, global_load_lds prefetch, ONE barrier per k-iter.
// NOTE (round 4 lesson): do NOT fuse the finalize via last-block-done +
// __threadfence -- agent-scope release fences cost ~60 us across 528 blocks
// on 8 non-coherent XCD L2s. Kernel-boundary hand-off is the cheap sync.
__launch_bounds__(256)
__global__ void gemm_fused(const short* __restrict__ zn,
                           float* __restrict__ rowsum,
                           float* __restrict__ spos) {
    __shared__ short At[2][128 * 32];
    __shared__ short Bt[2][128 * 32];

    // triangular decode (scalar, <=32 iters)
    int b = blockIdx.x, bi = 0, rowlen = 32;
    while (b >= rowlen) { b -= rowlen; rowlen--; bi++; }
    const int bj = bi + b;
    const int i0 = bi * 128;
    const int j0 = bj * 128;

    const int t = threadIdx.x;
    const int lane = t & 63, wave = t >> 6;
    const int wm = wave & 1, wn = wave >> 1;     // 2x2 waves -> 64x64 each
    const int quad = lane >> 4, l16 = lane & 15;

    // staging addresses: lane L covers row L>>2, 16B chunk L&3 ->
    // LDS offset = wave base + lane*16 (contiguous; global_load_lds rule)
    const int sr = lane >> 2;
    const int sc = (lane & 3) * 8;
    const short* gA0 = zn + (size_t)(i0 + wave * 32 + sr)      * D + sc;
    const short* gA1 = zn + (size_t)(i0 + wave * 32 + 16 + sr) * D + sc;
    const short* gB0 = zn + (size_t)(j0 + wave * 32 + sr)      * D + sc;
    const short* gB1 = zn + (size_t)(j0 + wave * 32 + 16 + sr) * D + sc;
    const int lo0 = (wave * 32)      * 32;
    const int lo1 = (wave * 32 + 16) * 32;

    floatx4 acc[4][4] = {};

    // prologue: stage k-tile 0 into buffer 0
    __builtin_amdgcn_global_load_lds(AS_GLOBAL(gA0), AS_LDS(&At[0][lo0]), 16, 0, 0);
    __builtin_amdgcn_global_load_lds(AS_GLOBAL(gA1), AS_LDS(&At[0][lo1]), 16, 0, 0);
    __builtin_amdgcn_global_load_lds(AS_GLOBAL(gB0), AS_LDS(&Bt[0][lo0]), 16, 0, 0);
    __builtin_amdgcn_global_load_lds(AS_GLOBAL(gB1), AS_LDS(&Bt[0][lo1]), 16, 0, 0);

    for (int kt = 0; kt < 16; ++kt) {
        const int cur = kt & 1;
        // drains vmcnt -> buf[cur] ready; all waves done reading buf[1-cur]
        __syncthreads();
        if (kt < 15) {
            const int nxt = 1 - cur;
            const int ko = (kt + 1) * 32;
            __builtin_amdgcn_global_load_lds(AS_GLOBAL(gA0 + ko), AS_LDS(&At[nxt][lo0]), 16, 0, 0);
            __builtin_amdgcn_global_load_lds(AS_GLOBAL(gA1 + ko), AS_LDS(&At[nxt][lo1]), 16, 0, 0);
            __builtin_amdgcn_global_load_lds(AS_GLOBAL(gB0 + ko), AS_LDS(&Bt[nxt][lo0]), 16, 0, 0);
            __builtin_amdgcn_global_load_lds(AS_GLOBAL(gB1 + ko), AS_LDS(&Bt[nxt][lo1]), 16, 0, 0);
        }
        short8 af[4], bf[4];
        #pragma unroll
        for (int tm = 0; tm < 4; ++tm)
            af[tm] = *(const short8*)(&At[cur][(wm*64 + tm*16 + l16) * 32 + quad*8]);
        #pragma unroll
        for (int tn = 0; tn < 4; ++tn)
            bf[tn] = *(const short8*)(&Bt[cur][(wn*64 + tn*16 + l16) * 32 + quad*8]);
        #pragma unroll
        for (int tm = 0; tm < 4; ++tm)
            #pragma unroll
            for (int tn = 0; tn < 4; ++tn)
                acc[tm][tn] = __builtin_amdgcn_mfma_f32_16x16x32_bf16(
                    af[tm], bf[tn], acc[tm][tn], 0, 0, 0);
    }

    // epilogue: e = exp(2s). Row sums -> rows I; column sums -> rows J
    // (off-diagonal tiles; S symmetric). 2 atomics/row + 2 atomics/col.
    float cs[4] = {0.f, 0.f, 0.f, 0.f};
    #pragma unroll
    for (int tm = 0; tm < 4; ++tm) {
        float rs[4] = {0.f, 0.f, 0.f, 0.f};
        #pragma unroll
        for (int tn = 0; tn < 4; ++tn)
            #pragma unroll
            for (int r = 0; r < 4; ++r) {
                float e = exp2f(acc[tm][tn][r] * EXP2_SCALE);
                rs[r] += e;
                cs[tn] += e;
            }
        #pragma unroll
        for (int r = 0; r < 4; ++r) {
            float v = rs[r];
            v += __shfl_xor(v, 1);
            v += __shfl_xor(v, 2);
            v += __shfl_xor(v, 4);
            v += __shfl_xor(v, 8);
            if (l16 == 0) {
                int gi = i0 + wm*64 + tm*16 + quad*4 + r;
                atomicAdd(&rowsum[gi], v);
            }
        }
    }
    if (bi != bj) {
        #pragma unroll
        for (int tn = 0; tn < 4; ++tn) {
            float v = cs[tn];
            v += __shfl_xor(v, 16);
            v += __shfl_xor(v, 32);
            if (quad == 0) {
                int gj = j0 + wn*64 + tn*16 + l16;
                atomicAdd(&rowsum[gj], v);
            }
        }
    }
    // positive pairs (j = i + 2048) live exactly in blocks bj == bi+16
    if (bj == bi + 16) {
        #pragma unroll
        for (int tm = 0; tm < 4; ++tm)
            #pragma unroll
            for (int tn = 0; tn < 4; ++tn)
                #pragma unroll
                for (int r = 0; r < 4; ++r) {
                    int li = wm*64 + tm*16 + quad*4 + r;   // local row
                    int lj = wn*64 + tn*16 + l16;          // local col
                    if (li == lj) {
                        float s = acc[tm][tn][r];
                        spos[i0 + li]         = s;
                        spos[i0 + li + BHALF] = s;
                    }
                }
    }
}

// ---------------- kernel 3: final loss ----------------
__global__ void finalize_kernel(const float* __restrict__ rowsum,
                                const float* __restrict__ spos,
                                float* __restrict__ out) {
    int t = threadIdx.x;                         // 1024 threads, 1 block
    float acc = 0.f;
    for (int i = t; i < N_TOT; i += 1024) {
        float sp = spos[i];
        float denom = rowsum[i] - E2 + exp2f(sp * EXP2_SCALE);
        acc += __logf(denom) - 2.0f * sp;
    }
    #pragma unroll
    for (int off = 32; off > 0; off >>= 1) acc += __shfl_xor(acc, off);
    __shared__ float red[16];
    if ((t & 63) == 0) red[t >> 6] = acc;
    __syncthreads();
    if (t == 0) {
        float s = 0.f;
        #pragma unroll
        for (int w = 0; w < 16; ++w) s += red[w];
        out[0] = s / (float)N_TOT;
    }
}

extern "C" void kernel_launch(void* const* d_in, const int* in_sizes, int n_in,
                              void* d_out, int out_size, void* d_ws, size_t ws_size,
                              hipStream_t stream) {
    const float* z_i = (const float*)d_in[0];
    const float* z_j = (const float*)d_in[1];
    float* out = (float*)d_out;

    char* ws = (char*)d_ws;
    short* zn     = (short*)ws;                                   // 4 MB
    float* rowsum = (float*)(ws + (size_t)N_TOT * D * 2);         // 16 KB
    float* spos   = rowsum + N_TOT;                               // 16 KB

    normalize_kernel<<<N_TOT / 4, 256, 0, stream>>>(z_i, z_j, zn, rowsum);
    gemm_fused<<<(32 * 33) / 2, 256, 0, stream>>>(zn, rowsum, spos);
    finalize_kernel<<<1, 1024, 0, stream>>>(rowsum, spos, out);
}

// Round 6
// 89.804 us; speedup vs baseline: 1.3733x; 1.0015x over previous
//
#include <hip/hip_runtime.h>
#include <hip/hip_bf16.h>

#define N_TOT 4096
#define D     512
#define BHALF 2048

// exp(2s) = 2^(s * 2*log2(e))
#define EXP2_SCALE 2.8853900817779268f
// exp(2*S_ii) for a normalized row (S_ii = 1 +- ~5e-3 in fp8; error in the
// final log is ~1e-5 -- negligible vs the 0.166 threshold)
#define E2 7.3890560989306495f

typedef __attribute__((ext_vector_type(4))) float floatx4;

#define AS_GLOBAL(p) ((const __attribute__((address_space(1))) void*)(p))
#define AS_LDS(p)    ((__attribute__((address_space(3))) void*)(p))

// s_waitcnt imm: vmcnt[3:0] | expcnt=7<<4 | lgkmcnt=15<<8 (ignore exp/lgkm)
#define WAITCNT_VM(n) (0xF70 | (n))

// ---------------- kernel 1: normalize rows, cast to fp8 e4m3 --------------
// 1024 blocks x 256 threads; one 64-lane wave per row, no LDS, no barrier.
// Also zeroes rowsum[] (ws is re-poisoned to 0xAA before every timed call).
__global__ void normalize_kernel(const float* __restrict__ z_i,
                                 const float* __restrict__ z_j,
                                 unsigned char* __restrict__ zn,
                                 float* __restrict__ rowsum) {
    const int wave = threadIdx.x >> 6, lane = threadIdx.x & 63;
    const int row = blockIdx.x * 4 + wave;
    const float* src = (row < BHALF) ? (z_i + (size_t)row * D)
                                     : (z_j + (size_t)(row - BHALF) * D);
    if (lane == 0) rowsum[row] = 0.0f;
    float4 v0 = ((const float4*)src)[lane];
    float4 v1 = ((const float4*)src)[lane + 64];
    float ss = v0.x*v0.x + v0.y*v0.y + v0.z*v0.z + v0.w*v0.w
             + v1.x*v1.x + v1.y*v1.y + v1.z*v1.z + v1.w*v1.w;
    #pragma unroll
    for (int off = 32; off > 0; off >>= 1) ss += __shfl_xor(ss, off);
    float inv = 1.0f / fmaxf(sqrtf(ss), 1e-8f);
    // pack 4 normalized floats -> 4 x e4m3 bytes (v_cvt_pk_fp8_f32, OCP fn)
    int w0 = __builtin_amdgcn_cvt_pk_fp8_f32(v0.x * inv, v0.y * inv, 0, false);
    w0     = __builtin_amdgcn_cvt_pk_fp8_f32(v0.z * inv, v0.w * inv, w0, true);
    int w1 = __builtin_amdgcn_cvt_pk_fp8_f32(v1.x * inv, v1.y * inv, 0, false);
    w1     = __builtin_amdgcn_cvt_pk_fp8_f32(v1.z * inv, v1.w * inv, w1, true);
    int* dst = (int*)(zn + (size_t)row * D);
    dst[lane]      = w0;
    dst[lane + 64] = w1;
}

// ---------------- kernel 2: fused symmetric GEMM + exp + row-sum ----------
// Triangular grid: 528 blocks of 256 threads; block -> (bi, bj), bj>=bi.
// fp8 e4m3 operands, 16x16x32_fp8_fp8 MFMA. Triple-buffered LDS with
// prefetch distance 2: raw s_barrier + explicit s_waitcnt vmcnt(2) instead
// of __syncthreads (which drains vmcnt(0) and collapses the pipeline).
// NOTE (round 4 lesson): no in-kernel cross-block fences -- agent-scope
// release costs ~60 us over 528 blocks; kernel boundary is the cheap sync.
__launch_bounds__(256)
__global__ void gemm_fused(const unsigned char* __restrict__ zn,
                           float* __restrict__ rowsum,
                           float* __restrict__ spos) {
    __shared__ unsigned char At[3][128 * 32];   // 4 KB per buffer
    __shared__ unsigned char Bt[3][128 * 32];

    // triangular decode (scalar, <=32 iters)
    int b = blockIdx.x, bi = 0, rowlen = 32;
    while (b >= rowlen) { b -= rowlen; rowlen--; bi++; }
    const int bj = bi + b;
    const int i0 = bi * 128;
    const int j0 = bj * 128;

    const int t = threadIdx.x;
    const int lane = t & 63, wave = t >> 6;
    const int wm = wave & 1, wn = wave >> 1;     // 2x2 waves -> 64x64 each
    const int quad = lane >> 4, l16 = lane & 15;

    // staging: per wave, 32 rows x 32 fp8 bytes = 1 KB = one 64x16B issue.
    // lane L -> row wave*32 + (L>>1), byte col (L&1)*16;
    // LDS offset = wave*1024 + L*16 (contiguous; global_load_lds rule)
    const int srow = wave * 32 + (lane >> 1);
    const int scol = (lane & 1) * 16;
    const unsigned char* gA = zn + (size_t)(i0 + srow) * D + scol;
    const unsigned char* gB = zn + (size_t)(j0 + srow) * D + scol;
    const int lo = srow * 32 + scol;             // == wave*1024 + lane*16

    floatx4 acc[4][4] = {};

    // prologue: stage k-tiles 0 and 1 into buffers 0 and 1
    __builtin_amdgcn_global_load_lds(AS_GLOBAL(gA),      AS_LDS(&At[0][lo]), 16, 0, 0);
    __builtin_amdgcn_global_load_lds(AS_GLOBAL(gB),      AS_LDS(&Bt[0][lo]), 16, 0, 0);
    __builtin_amdgcn_global_load_lds(AS_GLOBAL(gA + 32), AS_LDS(&At[1][lo]), 16, 0, 0);
    __builtin_amdgcn_global_load_lds(AS_GLOBAL(gB + 32), AS_LDS(&Bt[1][lo]), 16, 0, 0);

    #pragma unroll
    for (int kt = 0; kt < 16; ++kt) {
        const int cur = kt % 3;
        // own tile-kt DMAs complete (2 newer pairs may stay in flight)
        if (kt < 15) __builtin_amdgcn_s_waitcnt(WAITCNT_VM(2));
        else         __builtin_amdgcn_s_waitcnt(WAITCNT_VM(0));
        __builtin_amdgcn_s_barrier();            // all waves' tile-kt done
        __asm__ volatile("" ::: "memory");       // no LDS-read hoisting
        if (kt < 14) {
            const int nxt = (kt + 2) % 3;
            const int ko = (kt + 2) * 32;
            __builtin_amdgcn_global_load_lds(AS_GLOBAL(gA + ko), AS_LDS(&At[nxt][lo]), 16, 0, 0);
            __builtin_amdgcn_global_load_lds(AS_GLOBAL(gB + ko), AS_LDS(&Bt[nxt][lo]), 16, 0, 0);
        }
        long af[4], bf[4];
        #pragma unroll
        for (int tm = 0; tm < 4; ++tm)
            af[tm] = *(const long*)(&At[cur][(wm*64 + tm*16 + l16) * 32 + quad*8]);
        #pragma unroll
        for (int tn = 0; tn < 4; ++tn)
            bf[tn] = *(const long*)(&Bt[cur][(wn*64 + tn*16 + l16) * 32 + quad*8]);
        #pragma unroll
        for (int tm = 0; tm < 4; ++tm)
            #pragma unroll
            for (int tn = 0; tn < 4; ++tn)
                acc[tm][tn] = __builtin_amdgcn_mfma_f32_16x16x32_fp8_fp8(
                    af[tm], bf[tn], acc[tm][tn], 0, 0, 0);
    }

    // epilogue: e = exp(2s). Row sums -> rows I; column sums -> rows J
    // (off-diagonal tiles; S symmetric).
    float cs[4] = {0.f, 0.f, 0.f, 0.f};
    #pragma unroll
    for (int tm = 0; tm < 4; ++tm) {
        float rs[4] = {0.f, 0.f, 0.f, 0.f};
        #pragma unroll
        for (int tn = 0; tn < 4; ++tn)
            #pragma unroll
            for (int r = 0; r < 4; ++r) {
                float e = exp2f(acc[tm][tn][r] * EXP2_SCALE);
                rs[r] += e;
                cs[tn] += e;
            }
        #pragma unroll
        for (int r = 0; r < 4; ++r) {
            float v = rs[r];
            v += __shfl_xor(v, 1);
            v += __shfl_xor(v, 2);
            v += __shfl_xor(v, 4);
            v += __shfl_xor(v, 8);
            if (l16 == 0) {
                int gi = i0 + wm*64 + tm*16 + quad*4 + r;
                atomicAdd(&rowsum[gi], v);
            }
        }
    }
    if (bi != bj) {
        #pragma unroll
        for (int tn = 0; tn < 4; ++tn) {
            float v = cs[tn];
            v += __shfl_xor(v, 16);
            v += __shfl_xor(v, 32);
            if (quad == 0) {
                int gj = j0 + wn*64 + tn*16 + l16;
                atomicAdd(&rowsum[gj], v);
            }
        }
    }
    // positive pairs (j = i + 2048) live exactly in blocks bj == bi+16
    if (bj == bi + 16) {
        #pragma unroll
        for (int tm = 0; tm < 4; ++tm)
            #pragma unroll
            for (int tn = 0; tn < 4; ++tn)
                #pragma unroll
                for (int r = 0; r < 4; ++r) {
                    int li = wm*64 + tm*16 + quad*4 + r;   // local row
                    int lj = wn*64 + tn*16 + l16;          // local col
                    if (li == lj) {
                        float s = acc[tm][tn][r];
                        spos[i0 + li]         = s;
                        spos[i0 + li + BHALF] = s;
                    }
                }
    }
}

// ---------------- kernel 3: final loss ----------------
__global__ void finalize_kernel(const float* __restrict__ rowsum,
                                const float* __restrict__ spos,
                                float* __restrict__ out) {
    int t = threadIdx.x;                         // 1024 threads, 1 block
    float acc = 0.f;
    for (int i = t; i < N_TOT; i += 1024) {
        float sp = spos[i];
        float denom = rowsum[i] - E2 + exp2f(sp * EXP2_SCALE);
        acc += __logf(denom) - 2.0f * sp;
    }
    #pragma unroll
    for (int off = 32; off > 0; off >>= 1) acc += __shfl_xor(acc, off);
    __shared__ float red[16];
    if ((t & 63) == 0) red[t >> 6] = acc;
    __syncthreads();
    if (t == 0) {
        float s = 0.f;
        #pragma unroll
        for (int w = 0; w < 16; ++w) s += red[w];
        out[0] = s / (float)N_TOT;
    }
}

extern "C" void kernel_launch(void* const* d_in, const int* in_sizes, int n_in,
                              void* d_out, int out_size, void* d_ws, size_t ws_size,
                              hipStream_t stream) {
    const float* z_i = (const float*)d_in[0];
    const float* z_j = (const float*)d_in[1];
    float* out = (float*)d_out;

    char* ws = (char*)d_ws;
    unsigned char* zn = (unsigned char*)ws;                       // 2 MB
    float* rowsum = (float*)(ws + (size_t)N_TOT * D);             // 16 KB
    float* spos   = rowsum + N_TOT;                               // 16 KB

    normalize_kernel<<<N_TOT / 4, 256, 0, stream>>>(z_i, z_j, zn, rowsum);
    gemm_fused<<<(32 * 33) / 2, 256, 0, stream>>>(zn, rowsum, spos);
    finalize_kernel<<<1, 1024, 0, stream>>>(rowsum, spos, out);
}